// Round 6
// baseline (115.763 us; speedup 1.0000x reference)
//
#include <hip/hip_runtime.h>
#include <math.h>

#define NB 4
#define NT 1024
#define NPIX 1296
#define NBINS 512
#define LOOKUP 101
#define PADW 50
#define ODIM 128
#define TT 4                 // t-values per sims block
#define WROWS (TT + 2 * PADW) // 108 window rows per block

typedef _Float16 v2h __attribute__((ext_vector_type(2)));

__device__ inline float dot2(unsigned a, unsigned b, float acc) {
    union U { unsigned u; v2h h; } ua, ub;
    ua.u = a; ub.u = b;
#if __has_builtin(__builtin_amdgcn_fdot2)
    return __builtin_amdgcn_fdot2(ua.h, ub.h, acc, false);
#else
    return acc + (float)ua.h.x * (float)ub.h.x + (float)ua.h.y * (float)ub.h.y;
#endif
}

// ---------------- Kernel A: per-frame 512-bin histogram -> L2-normalized f16 row
// Direct int4-group loads interleaved with LDS atomics (no staging barrier:
// keeps the HBM stream overlapped with binning). R5's LDS-staged variant was
// ~7 us slower; R4's nontemporal loads were ~16 us slower (cache-line overlap
// between 48B-stride lanes re-fetched from HBM).
__global__ __launch_bounds__(256) void hist_kernel(const int* __restrict__ frames,
                                                   unsigned short* __restrict__ X) {
    const int frame = blockIdx.x;
    const int tid = threadIdx.x;
    __shared__ unsigned int hist[NBINS];
    for (int i = tid; i < NBINS; i += 256) hist[i] = 0u;
    __syncthreads();

    const int4* f4 = (const int4*)(frames + (size_t)frame * NPIX * 3);
    for (int g = tid; g < NPIX / 4; g += 256) {   // 324 groups of 4 px
        int4 a = f4[g * 3 + 0];
        int4 b = f4[g * 3 + 1];
        int4 c = f4[g * 3 + 2];
        int v[12] = {a.x, a.y, a.z, a.w, b.x, b.y, b.z, b.w, c.x, c.y, c.z, c.w};
#pragma unroll
        for (int p = 0; p < 4; ++p) {
            int bin = ((v[3 * p] >> 5) << 6) | ((v[3 * p + 1] >> 5) << 3) | (v[3 * p + 2] >> 5);
            atomicAdd(&hist[bin], 1u);
        }
    }
    __syncthreads();

    float local = 0.f;
    for (int i = tid; i < NBINS; i += 256) {
        float h = (float)hist[i];
        local += h * h;
    }
    for (int off = 32; off >= 1; off >>= 1) local += __shfl_xor(local, off, 64);
    __shared__ float wsum[4];
    if ((tid & 63) == 0) wsum[tid >> 6] = local;
    __syncthreads();
    float inv = 1.0f / fmaxf(sqrtf(wsum[0] + wsum[1] + wsum[2] + wsum[3]), 1e-12f);

    unsigned* xrow = (unsigned*)(X + (size_t)frame * NBINS);
    union U { _Float16 h[2]; unsigned u; } pk;
    pk.h[0] = (_Float16)((float)hist[2 * tid] * inv);
    pk.h[1] = (_Float16)((float)hist[2 * tid + 1] * inv);
    xrow[tid] = pk.u;
}

// ---------------- Kernel B (fused): banded sims + FC + ReLU, TT=4 t per block
// 256 threads = 16 groups of 16 lanes. t-row K-slices live in registers;
// each window-row A-slice is loaded once from L2 and feeds 4 dots.
__global__ __launch_bounds__(256) void simsfc_kernel(const unsigned short* __restrict__ X,
                                                     const float* __restrict__ w,
                                                     const float* __restrict__ bias,
                                                     float* __restrict__ out) {
    const int bid = blockIdx.x;
    // XCD swizzle: each XCD owns a contiguous 512-frame slice of X (L2-resident)
    const int tile = ((bid & 7) << 7) | (bid >> 3);   // 0..1023
    const int b = tile >> 8;                           // 256 tiles per batch
    const int t0 = (tile & 255) * TT;
    const int tid = threadIdx.x;
    const int gid = tid >> 4;        // 0..15 lane-group
    const int kl = tid & 15;         // K-slice lane within group

    __shared__ __align__(16) uint4 st[TT][64];   // 4 t-rows, f16, 4 KB
    __shared__ float win_s[TT][LOOKUP + 3];

    const uint4* Xb4 = (const uint4*)(X + (size_t)b * NT * NBINS);

    // stage the 4 t-rows (coalesced: 256 consecutive uint4)
    {
        int dt = tid >> 6, col = tid & 63;
        st[dt][col] = Xb4[(size_t)(t0 + dt) * 64 + col];
    }
    for (int i = tid; i < TT * (LOOKUP + 3); i += 256) ((float*)win_s)[i] = 0.f;
    __syncthreads();

    // per-lane register cache of the 4 t-row K-slices (16 uint4)
    uint4 tA[TT][4];
#pragma unroll
    for (int dt = 0; dt < TT; ++dt)
#pragma unroll
        for (int i = 0; i < 4; ++i) tA[dt][i] = st[dt][kl + 16 * i];

    for (int it = 0; it < 7; ++it) {
        const int joff = it * 16 + gid;            // 0..111, window-row index
        if (joff >= WROWS) continue;
        const int j = t0 - PADW + joff;
        if (j < 0 || j >= NT) continue;            // win stays zero
        uint4 A[4];
        const uint4* xj = Xb4 + (size_t)j * 64;
#pragma unroll
        for (int i = 0; i < 4; ++i) A[i] = xj[kl + 16 * i];
#pragma unroll
        for (int dt = 0; dt < TT; ++dt) {
            float s = 0.f;
#pragma unroll
            for (int i = 0; i < 4; ++i) {
                s = dot2(A[i].x, tA[dt][i].x, s);
                s = dot2(A[i].y, tA[dt][i].y, s);
                s = dot2(A[i].z, tA[dt][i].z, s);
                s = dot2(A[i].w, tA[dt][i].w, s);
            }
            s += __shfl_xor(s, 1, 64);
            s += __shfl_xor(s, 2, 64);
            s += __shfl_xor(s, 4, 64);
            s += __shfl_xor(s, 8, 64);
            const int l = joff - dt;
            if (kl == 0 && (unsigned)l <= 100u) win_s[dt][l] = s;
        }
    }
    __syncthreads();

    // FC + ReLU: thread -> channel ch, t-rows {g2, g2+2}; one w load feeds 2 rows
    const int ch = tid & 127;
    const int g2 = tid >> 7;
    float acc0 = bias[ch], acc1 = acc0;
#pragma unroll 4
    for (int l = 0; l < LOOKUP; ++l) {
        float wv = w[l * ODIM + ch];
        acc0 = fmaf(win_s[g2][l], wv, acc0);
        acc1 = fmaf(win_s[g2 + 2][l], wv, acc1);
    }
    float* o0 = out + ((size_t)(b * NT + t0 + g2) * ODIM) + ch;
    o0[0] = fmaxf(acc0, 0.f);
    o0[2 * ODIM] = fmaxf(acc1, 0.f);
}

extern "C" void kernel_launch(void* const* d_in, const int* in_sizes, int n_in,
                              void* d_out, int out_size, void* d_ws, size_t ws_size,
                              hipStream_t stream) {
    const int*   frames = (const int*)d_in[0];
    const float* fc_w   = (const float*)d_in[1];
    const float* fc_b   = (const float*)d_in[2];
    float* out = (float*)d_out;

    unsigned short* X = (unsigned short*)d_ws;   // 4096*512 f16 = 4 MB

    hist_kernel  <<<NB * NT, 256, 0, stream>>>(frames, X);
    simsfc_kernel<<<NB * NT / TT, 256, 0, stream>>>(X, fc_w, fc_b, out);
}

// Round 7
// 113.769 us; speedup vs baseline: 1.0175x; 1.0175x over previous
//
#include <hip/hip_runtime.h>
#include <math.h>

#define NB 4
#define NT 1024
#define NPIX 1296
#define NBINS 512
#define LOOKUP 101
#define PADW 50
#define ODIM 128
#define TT 4                 // t-values per sims block
#define WROWS (TT + 2 * PADW) // 108 window rows per block

typedef _Float16 v2h __attribute__((ext_vector_type(2)));

__device__ inline float dot2(unsigned a, unsigned b, float acc) {
    union U { unsigned u; v2h h; } ua, ub;
    ua.u = a; ub.u = b;
#if __has_builtin(__builtin_amdgcn_fdot2)
    return __builtin_amdgcn_fdot2(ua.h, ub.h, acc, false);
#else
    return acc + (float)ua.h.x * (float)ub.h.x + (float)ua.h.y * (float)ub.h.y;
#endif
}

// ---------------- Kernel A: wave-private histograms, ZERO block barriers.
// Block = 4 independent waves; wave w owns frame 4*bid+w and a private 2 KB
// LDS hist. LDS ops are in-order within a wave, so no syncs are needed
// anywhere; HBM loads stream continuously past the binning.
__global__ __launch_bounds__(256) void hist_kernel(const int* __restrict__ frames,
                                                   unsigned short* __restrict__ X) {
    const int wv = threadIdx.x >> 6;
    const int lane = threadIdx.x & 63;
    const int frame = blockIdx.x * 4 + wv;

    __shared__ unsigned int hist[4][NBINS];     // 8 KB, wave-private slices
    unsigned int* h = hist[wv];

#pragma unroll
    for (int k = 0; k < NBINS / 64; ++k) h[lane + 64 * k] = 0u;

    const int4* f4 = (const int4*)(frames + (size_t)frame * NPIX * 3);
    for (int g = lane; g < NPIX / 4; g += 64) {   // 324 groups of 4 px, 5-6 iters
        int4 a = f4[g * 3 + 0];
        int4 b = f4[g * 3 + 1];
        int4 c = f4[g * 3 + 2];
        int v[12] = {a.x, a.y, a.z, a.w, b.x, b.y, b.z, b.w, c.x, c.y, c.z, c.w};
#pragma unroll
        for (int p = 0; p < 4; ++p) {
            int bin = ((v[3 * p] >> 5) << 6) | ((v[3 * p + 1] >> 5) << 3) | (v[3 * p + 2] >> 5);
            atomicAdd(&h[bin], 1u);
        }
    }

    // per-wave sumsq reduce; keep the 8 counts in registers for the store
    float cnt[8];
    float local = 0.f;
#pragma unroll
    for (int k = 0; k < 8; ++k) {
        cnt[k] = (float)h[lane + 64 * k];
        local += cnt[k] * cnt[k];
    }
    for (int off = 32; off >= 1; off >>= 1) local += __shfl_xor(local, off, 64);
    float inv = 1.0f / fmaxf(sqrtf(local), 1e-12f);

    // 8 coalesced 128B stores: lane i stores bin (i + 64k) as f16 bits
    unsigned short* xr = X + (size_t)frame * NBINS;
#pragma unroll
    for (int k = 0; k < 8; ++k) {
        union { _Float16 h16; unsigned short u; } cv;
        cv.h16 = (_Float16)(cnt[k] * inv);
        xr[lane + 64 * k] = cv.u;
    }
}

// ---------------- Kernel B (fused): banded sims + FC + ReLU, TT=4 t per block
// 256 threads = 16 groups of 16 lanes. t-row K-slices live in registers;
// each window-row A-slice is loaded once from L2 and feeds 4 dots.
__global__ __launch_bounds__(256) void simsfc_kernel(const unsigned short* __restrict__ X,
                                                     const float* __restrict__ w,
                                                     const float* __restrict__ bias,
                                                     float* __restrict__ out) {
    const int bid = blockIdx.x;
    // XCD swizzle: each XCD owns a contiguous 512-frame slice of X (L2-resident)
    const int tile = ((bid & 7) << 7) | (bid >> 3);   // 0..1023
    const int b = tile >> 8;                           // 256 tiles per batch
    const int t0 = (tile & 255) * TT;
    const int tid = threadIdx.x;
    const int gid = tid >> 4;        // 0..15 lane-group
    const int kl = tid & 15;         // K-slice lane within group

    __shared__ __align__(16) uint4 st[TT][64];   // 4 t-rows, f16, 4 KB
    __shared__ float win_s[TT][LOOKUP + 3];

    const uint4* Xb4 = (const uint4*)(X + (size_t)b * NT * NBINS);

    // stage the 4 t-rows (coalesced: 256 consecutive uint4)
    {
        int dt = tid >> 6, col = tid & 63;
        st[dt][col] = Xb4[(size_t)(t0 + dt) * 64 + col];
    }
    for (int i = tid; i < TT * (LOOKUP + 3); i += 256) ((float*)win_s)[i] = 0.f;
    __syncthreads();

    // per-lane register cache of the 4 t-row K-slices (16 uint4)
    uint4 tA[TT][4];
#pragma unroll
    for (int dt = 0; dt < TT; ++dt)
#pragma unroll
        for (int i = 0; i < 4; ++i) tA[dt][i] = st[dt][kl + 16 * i];

    for (int it = 0; it < 7; ++it) {
        const int joff = it * 16 + gid;            // 0..111, window-row index
        if (joff >= WROWS) continue;
        const int j = t0 - PADW + joff;
        if (j < 0 || j >= NT) continue;            // win stays zero
        uint4 A[4];
        const uint4* xj = Xb4 + (size_t)j * 64;
#pragma unroll
        for (int i = 0; i < 4; ++i) A[i] = xj[kl + 16 * i];
#pragma unroll
        for (int dt = 0; dt < TT; ++dt) {
            float s = 0.f;
#pragma unroll
            for (int i = 0; i < 4; ++i) {
                s = dot2(A[i].x, tA[dt][i].x, s);
                s = dot2(A[i].y, tA[dt][i].y, s);
                s = dot2(A[i].z, tA[dt][i].z, s);
                s = dot2(A[i].w, tA[dt][i].w, s);
            }
            s += __shfl_xor(s, 1, 64);
            s += __shfl_xor(s, 2, 64);
            s += __shfl_xor(s, 4, 64);
            s += __shfl_xor(s, 8, 64);
            const int l = joff - dt;
            if (kl == 0 && (unsigned)l <= 100u) win_s[dt][l] = s;
        }
    }
    __syncthreads();

    // FC + ReLU: thread -> channel ch, t-rows {g2, g2+2}; one w load feeds 2 rows
    const int ch = tid & 127;
    const int g2 = tid >> 7;
    float acc0 = bias[ch], acc1 = acc0;
#pragma unroll 4
    for (int l = 0; l < LOOKUP; ++l) {
        float wv = w[l * ODIM + ch];
        acc0 = fmaf(win_s[g2][l], wv, acc0);
        acc1 = fmaf(win_s[g2 + 2][l], wv, acc1);
    }
    float* o0 = out + ((size_t)(b * NT + t0 + g2) * ODIM) + ch;
    o0[0] = fmaxf(acc0, 0.f);
    o0[2 * ODIM] = fmaxf(acc1, 0.f);
}

extern "C" void kernel_launch(void* const* d_in, const int* in_sizes, int n_in,
                              void* d_out, int out_size, void* d_ws, size_t ws_size,
                              hipStream_t stream) {
    const int*   frames = (const int*)d_in[0];
    const float* fc_w   = (const float*)d_in[1];
    const float* fc_b   = (const float*)d_in[2];
    float* out = (float*)d_out;

    unsigned short* X = (unsigned short*)d_ws;   // 4096*512 f16 = 4 MB

    hist_kernel  <<<NB * NT / 4, 256, 0, stream>>>(frames, X);
    simsfc_kernel<<<NB * NT / TT, 256, 0, stream>>>(X, fc_w, fc_b, out);
}

// Round 8
// 113.104 us; speedup vs baseline: 1.0235x; 1.0059x over previous
//
#include <hip/hip_runtime.h>
#include <math.h>

#define NB 4
#define NT 1024
#define NPIX 1296
#define NBINS 512
#define LOOKUP 101
#define PADW 50
#define ODIM 128
#define MT 16                 // t-rows per sims block (MFMA M-tile)
#define NWIN 116              // j-window rows actually used: n = m + l in [0,115]
#define WPAD 104              // win_s row stride (floats)

typedef _Float16 v8h __attribute__((ext_vector_type(8)));
typedef float v4f __attribute__((ext_vector_type(4)));

// ---------------- Kernel A: wave-private histograms, zero block barriers.
// (3 structural variants benched equal -> this is at its HBM/limiter floor.)
__global__ __launch_bounds__(256) void hist_kernel(const int* __restrict__ frames,
                                                   unsigned short* __restrict__ X) {
    const int wv = threadIdx.x >> 6;
    const int lane = threadIdx.x & 63;
    const int frame = blockIdx.x * 4 + wv;

    __shared__ unsigned int hist[4][NBINS];
    unsigned int* h = hist[wv];

#pragma unroll
    for (int k = 0; k < NBINS / 64; ++k) h[lane + 64 * k] = 0u;

    const int4* f4 = (const int4*)(frames + (size_t)frame * NPIX * 3);
    for (int g = lane; g < NPIX / 4; g += 64) {
        int4 a = f4[g * 3 + 0];
        int4 b = f4[g * 3 + 1];
        int4 c = f4[g * 3 + 2];
        int v[12] = {a.x, a.y, a.z, a.w, b.x, b.y, b.z, b.w, c.x, c.y, c.z, c.w};
#pragma unroll
        for (int p = 0; p < 4; ++p) {
            int bin = ((v[3 * p] >> 5) << 6) | ((v[3 * p + 1] >> 5) << 3) | (v[3 * p + 2] >> 5);
            atomicAdd(&h[bin], 1u);
        }
    }

    float cnt[8];
    float local = 0.f;
#pragma unroll
    for (int k = 0; k < 8; ++k) {
        cnt[k] = (float)h[lane + 64 * k];
        local += cnt[k] * cnt[k];
    }
    for (int off = 32; off >= 1; off >>= 1) local += __shfl_xor(local, off, 64);
    float inv = 1.0f / fmaxf(sqrtf(local), 1e-12f);

    unsigned short* xr = X + (size_t)frame * NBINS;
#pragma unroll
    for (int k = 0; k < 8; ++k) {
        union { _Float16 h16; unsigned short u; } cv;
        cv.h16 = (_Float16)(cnt[k] * inv);
        xr[lane + 64 * k] = cv.u;
    }
}

// ---------------- Kernel B: MFMA banded sims + VALU FC + ReLU.
// Block = 16 t-rows, 512 threads = 8 waves; wave w owns n-tile w (cols 16w..16w+15).
// C[16x128] = A[16x512] * B[512x128], K-steps of 32 via mfma_f32_16x16x32_f16.
// A frag: lane holds A[m=lane&15][k=8*(lane>>4)+j] -> 16B contiguous from X row t0+m.
// B frag: lane holds B[k][n=lane&15]              -> 16B contiguous from X row j(n).
// Epilogue: C elem (reg r, lane L) is sims for m=4*(L>>4)+r, n=ntile*16+(L&15);
// win l = n - m, j = t0 - 50 + n.
__global__ __launch_bounds__(512) void simsfc_kernel(const unsigned short* __restrict__ Xu,
                                                     const float* __restrict__ w,
                                                     const float* __restrict__ bias,
                                                     float* __restrict__ out) {
    const int bid = blockIdx.x;
    // XCD swizzle: 32 consecutive tiles (512 t's) per XCD -> B-window slice L2-resident
    const int tile = ((bid & 7) << 5) | (bid >> 3);    // 0..255
    const int b = tile >> 6;                            // 64 tiles per batch
    const int t0 = (tile & 63) * MT;
    const int tid = threadIdx.x;
    const int L = tid & 63;
    const int ntile = tid >> 6;        // 0..7

    const _Float16* Xh = (const _Float16*)Xu + (size_t)b * NT * NBINS;

    __shared__ float win_s[MT][WPAD];

    // fragment base pointers (immediate-offset friendly: +64B per k-step)
    const _Float16* Ap = Xh + (size_t)(t0 + (L & 15)) * NBINS + 8 * (L >> 4);
    const int n = ntile * 16 + (L & 15);
    const int jl = t0 - PADW + n;
    const int jc = min(max(jl, 0), NT - 1);
    const _Float16* Bp = Xh + (size_t)jc * NBINS + 8 * (L >> 4);

    v4f acc = {0.f, 0.f, 0.f, 0.f};
#pragma unroll
    for (int s = 0; s < 16; ++s) {
        v8h a = *(const v8h*)(Ap + 32 * s);
        v8h bb = *(const v8h*)(Bp + 32 * s);
        acc = __builtin_amdgcn_mfma_f32_16x16x32_f16(a, bb, acc, 0, 0, 0);
    }

    // epilogue: scatter into win_s (one writer per (m,l) cell; n = m + l unique)
    const bool jvalid = (jl >= 0) && (jl < NT);
#pragma unroll
    for (int r = 0; r < 4; ++r) {
        const int m = 4 * (L >> 4) + r;
        const int l = n - m;
        if ((unsigned)l <= 100u) win_s[m][l] = jvalid ? acc[r] : 0.f;
    }
    __syncthreads();

    // FC + ReLU: thread -> (m = tid>>5, 4 channels). w rows L2-resident.
    const int m = tid >> 5;
    const int ch = (tid & 31) * 4;
    v4f a4 = *(const v4f*)(bias + ch);
#pragma unroll 4
    for (int l = 0; l < LOOKUP; ++l) {
        float wl = win_s[m][l];
        v4f wv = *(const v4f*)(w + l * ODIM + ch);
        a4.x = fmaf(wl, wv.x, a4.x);
        a4.y = fmaf(wl, wv.y, a4.y);
        a4.z = fmaf(wl, wv.z, a4.z);
        a4.w = fmaf(wl, wv.w, a4.w);
    }
    a4.x = fmaxf(a4.x, 0.f); a4.y = fmaxf(a4.y, 0.f);
    a4.z = fmaxf(a4.z, 0.f); a4.w = fmaxf(a4.w, 0.f);
    *(v4f*)(out + (size_t)(b * NT + t0 + m) * ODIM + ch) = a4;
}

extern "C" void kernel_launch(void* const* d_in, const int* in_sizes, int n_in,
                              void* d_out, int out_size, void* d_ws, size_t ws_size,
                              hipStream_t stream) {
    const int*   frames = (const int*)d_in[0];
    const float* fc_w   = (const float*)d_in[1];
    const float* fc_b   = (const float*)d_in[2];
    float* out = (float*)d_out;

    unsigned short* X = (unsigned short*)d_ws;   // 4096*512 f16 = 4 MB

    hist_kernel  <<<NB * NT / 4, 256, 0, stream>>>(frames, X);
    simsfc_kernel<<<NB * NT / MT, 512, 0, stream>>>(X, fc_w, fc_b, out);
}